// Round 7
// baseline (405.369 us; speedup 1.0000x reference)
//
#include <hip/hip_runtime.h>
#include <math.h>

#define Bn 4096
#define Tn 512
#define Vn 57
#define En 20
#define Hn 128
#define On 18
#define ROWS 16          // batch rows per block (= MFMA N)
#define NTHR 256         // 4 waves, one per SIMD; each wave computes 32 h_new cols
#define NBLK (Bn / ROWS) // 256 blocks -> 1 per CU (static LDS > 80KB)
#define KC 5             // K = 160 = 128 (h) + 20 (emb) + 1 (bias) + 11 pad
#define NKB 20           // k-blocks of 8 halfs
#define BUFH (NKB * 16 * 8)  // 2560 halfs per fragment-major buffer
#define ESTR 40          // embT row stride (halfs)
#define XSTR 513         // staged x row stride (ints): bank=(r+t)%32, conflict-free
#define HFSTR 132        // final-h fp32 row stride

typedef _Float16 half8  __attribute__((ext_vector_type(8)));
typedef _Float16 half4  __attribute__((ext_vector_type(4)));
typedef float    floatx4 __attribute__((ext_vector_type(4)));

__device__ __forceinline__ float fast_tanh(float x) {
    float e = __expf(2.0f * x);
    return 1.0f - __fdividef(2.0f, e + 1.0f);
}

// (256, 1): min 1 wave/EU -> VGPR cap 512. The weight fragments (80 VGPRs) MUST
// stay register-resident; default heuristic allocated 88 and spilled them to
// scratch (FETCH_SIZE 4.5GB in R3-R6 = per-step reload of A operands).
__launch_bounds__(NTHR, 1)
__global__ void rnn_mfma_kernel(const int* __restrict__ x,
                                const int* __restrict__ xlen,
                                const float* __restrict__ emb,
                                const float* __restrict__ W_ih,
                                const float* __restrict__ W_hh,
                                const float* __restrict__ b_ih,
                                const float* __restrict__ b_hh,
                                const float* __restrict__ W_out,
                                const float* __restrict__ b_out,
                                float* __restrict__ out)
{
    // Fragment-major B operand: slot s = kblock*16 + batch_row holds halfs
    // [kblock*8 .. +8) of that row. Wave b128 read = 64 consecutive slots
    // (conflict-free); h-store = 64 consecutive 8B half-slots (conflict-free).
    __shared__ __align__(16) _Float16 sB[2][BUFH];
    __shared__ __align__(16) _Float16 sEmb[Vn * ESTR];  // cols 0..19 emb, 20 = 1.0, rest 0
    __shared__ __align__(16) float    sHf[ROWS * HFSTR];
    __shared__ int sX[ROWS * XSTR];
    __shared__ float sLogit[ROWS][On];
    __shared__ float sMLS[ROWS];
    __shared__ float sPad[6400];   // 25.6KB: total LDS ~83KB -> exactly 1 block/CU

    const int tid  = threadIdx.x;
    const int blk  = blockIdx.x;
    const int row0 = blk * ROWS;

    // volatile touch: sPad cannot be eliminated, preserving the LDS footprint
    ((volatile float*)sPad)[tid] = 0.0f;

    const int w    = tid >> 6;       // wave 0..3 -> cols [32w, 32w+32)
    const int lane = tid & 63;
    const int n    = lane & 15;      // MFMA lane index (batch for B/C, row-in-tile for A)
    const int q    = lane >> 4;      // quad

    // ---- A operands (static in VGPRs): rows of [W_hh | W_ih | bias | 0], fp16 hi + 2048*lo
    half8 Ah0[KC], Al0[KC], Ah1[KC], Al1[KC];
    #pragma unroll
    for (int kc = 0; kc < 4; ++kc) {
        const float* p0 = &W_hh[(32 * w + n) * Hn + kc * 32 + q * 8];
        const float* p1 = &W_hh[(32 * w + 16 + n) * Hn + kc * 32 + q * 8];
        #pragma unroll
        for (int i = 0; i < 8; ++i) {
            float v0 = p0[i], v1 = p1[i];
            _Float16 h0 = (_Float16)v0, h1 = (_Float16)v1;
            Ah0[kc][i] = h0; Al0[kc][i] = (_Float16)((v0 - (float)h0) * 2048.0f);
            Ah1[kc][i] = h1; Al1[kc][i] = (_Float16)((v1 - (float)h1) * 2048.0f);
        }
    }
    {   // kc=4: W_ih cols 0..19, bias at k-col 20, zero beyond
        #pragma unroll
        for (int i = 0; i < 8; ++i) {
            int e = q * 8 + i;
            float v0 = 0.0f, v1 = 0.0f;
            if (e < En) {
                v0 = W_ih[(32 * w + n) * En + e];
                v1 = W_ih[(32 * w + 16 + n) * En + e];
            } else if (e == 20) {
                v0 = b_ih[32 * w + n]      + b_hh[32 * w + n];
                v1 = b_ih[32 * w + 16 + n] + b_hh[32 * w + 16 + n];
            }
            _Float16 h0 = (_Float16)v0, h1 = (_Float16)v1;
            Ah0[4][i] = h0; Al0[4][i] = (_Float16)((v0 - (float)h0) * 2048.0f);
            Ah1[4][i] = h1; Al1[4][i] = (_Float16)((v1 - (float)h1) * 2048.0f);
        }
    }

    // ---- build embT (fp16) with constant-1 bias column
    for (int idx = tid; idx < Vn * 32; idx += NTHR) {
        int c = idx >> 5, j = idx & 31;
        float v = (j < En) ? emb[c * En + j] : (j == 20 ? 1.0f : 0.0f);
        sEmb[c * ESTR + j] = (_Float16)v;
    }
    // ---- stage vocab ids (int4-vectorized; 512 % 4 == 0 -> no row crossing)
    for (int idx = tid * 4; idx < ROWS * Tn; idx += NTHR * 4) {
        int4 v = *(const int4*)&x[row0 * Tn + idx];
        int r = idx >> 9, t = idx & 511;
        sX[r * XSTR + t]     = v.x;
        sX[r * XSTR + t + 1] = v.y;
        sX[r * XSTR + t + 2] = v.z;
        sX[r * XSTR + t + 3] = v.w;
    }
    // ---- zero both fragment buffers (h0 = 0)
    for (int idx = tid; idx < 2 * BUFH / 8; idx += NTHR)
        ((float4*)sB)[idx] = make_float4(0.f, 0.f, 0.f, 0.f);
    __syncthreads();

    const int Lmax  = xlen[row0];    // sorted descending -> block trip count
    const int len_n = xlen[row0 + n];

    // ---- xe(0) staging: wave w writes kblock 16+w for all 16 rows (lanes 0..15)
    if (lane < 16) {
        int id0 = sX[lane * XSTR + 0];
        half8 xe = *(const half8*)&sEmb[id0 * ESTR + w * 8];
        *(half8*)&sB[0][(16 + w) * 128 + lane * 8] = xe;
    }
    __syncthreads();

    float hreg[8] = {0.f, 0.f, 0.f, 0.f, 0.f, 0.f, 0.f, 0.f};

    const int bbase = q * 128 + n * 8;                       // B-read lane base (halfs)
    const int kbA   = 4 * w + (q >> 1);                      // tile0 store kblock
    const int sadr  = kbA * 128 + n * 8 + 4 * (q & 1);       // tile0 store addr (halfs)

    // id pipeline: id_use = token id at t+1 (register-carried across the barrier,
    // so the per-step chain is only sEmb-gather -> write, no sX dependency)
    int id_use = 0;
    if (lane < 16) id_use = sX[lane * XSTR + (Lmax > 1 ? 1 : 0)];

    for (int t = 0; t < Lmax; ++t) {
        const _Float16* bp = &sB[t & 1][0];
        _Float16*       np = &sB[(t & 1) ^ 1][0];

        // xe(t+1) gather from prefetched id (issues immediately after barrier)
        half8 xe;
        if (lane < 16)
            xe = *(const half8*)&sEmb[id_use * ESTR + w * 8];
        // prefetch id for t+2 (consumed next iteration)
        int tnn = (t + 2 < Lmax) ? t + 2 : Lmax - 1;
        int id_next = 0;
        if (lane < 16) id_next = sX[lane * XSTR + tnn];

        // B operand: 5 b128 reads, 64 consecutive slots per read -> conflict-free
        half8 b[KC];
        #pragma unroll
        for (int kc = 0; kc < KC; ++kc)
            b[kc] = *(const half8*)&bp[bbase + kc * 512];

        // D = [W_hh|W_ih|b] . [h; xe; 1] for 2 col-tiles, hi + lo/2048 split
        floatx4 a0h = {0.f,0.f,0.f,0.f}, a0l = {0.f,0.f,0.f,0.f};
        floatx4 a1h = {0.f,0.f,0.f,0.f}, a1l = {0.f,0.f,0.f,0.f};
        #pragma unroll
        for (int kc = 0; kc < KC; ++kc) {
            a0h = __builtin_amdgcn_mfma_f32_16x16x32_f16(Ah0[kc], b[kc], a0h, 0, 0, 0);
            a1h = __builtin_amdgcn_mfma_f32_16x16x32_f16(Ah1[kc], b[kc], a1h, 0, 0, 0);
            a0l = __builtin_amdgcn_mfma_f32_16x16x32_f16(Al0[kc], b[kc], a0l, 0, 0, 0);
            a1l = __builtin_amdgcn_mfma_f32_16x16x32_f16(Al1[kc], b[kc], a1l, 0, 0, 0);
        }

        // C layout: lane(n,q) reg i -> col 32w+4q+i (tile0) / +16 (tile1), batch n
        const bool upd = (t < len_n);
        half4 s0, s1;
        #pragma unroll
        for (int i = 0; i < 4; ++i) {
            float v0 = fast_tanh(a0h[i] + a0l[i] * (1.0f / 2048.0f));
            float v1 = fast_tanh(a1h[i] + a1l[i] * (1.0f / 2048.0f));
            hreg[i]     = upd ? v0 : hreg[i];
            hreg[4 + i] = upd ? v1 : hreg[4 + i];
            s0[i] = (_Float16)hreg[i];
            s1[i] = (_Float16)hreg[4 + i];
        }
        *(half4*)&np[sadr]       = s0;   // consecutive 8B half-slots -> conflict-free
        *(half4*)&np[sadr + 256] = s1;
        if (lane < 16)
            *(half8*)&np[(16 + w) * 128 + lane * 8] = xe;

        id_use = id_next;
        __syncthreads();   // double-buffered -> one barrier per step
    }

    // ---- publish final fp32 h
    {
        float4 f0, f1;
        f0.x = hreg[0]; f0.y = hreg[1]; f0.z = hreg[2]; f0.w = hreg[3];
        f1.x = hreg[4]; f1.y = hreg[5]; f1.z = hreg[6]; f1.w = hreg[7];
        *(float4*)&sHf[n * HFSTR + 32 * w + 4 * q]      = f0;
        *(float4*)&sHf[n * HFSTR + 32 * w + 16 + 4 * q] = f1;
    }
    __syncthreads();

    // ---- epilogue: logits = relu(h) @ W_out^T + b_out, then log_softmax
    for (int it = tid; it < ROWS * On; it += NTHR) {
        int r = it / On, c = it % On;
        float acc = b_out[c];
        for (int k = 0; k < Hn; ++k) {
            float hv = sHf[r * HFSTR + k];
            hv = hv > 0.0f ? hv : 0.0f;
            acc = fmaf(hv, W_out[c * Hn + k], acc);
        }
        sLogit[r][c] = acc;
    }
    __syncthreads();

    if (tid < ROWS) {
        float m = -INFINITY;
        #pragma unroll
        for (int c = 0; c < On; ++c) m = fmaxf(m, sLogit[tid][c]);
        float s = 0.0f;
        #pragma unroll
        for (int c = 0; c < On; ++c) s += __expf(sLogit[tid][c] - m);
        sMLS[tid] = m + __logf(s);
    }
    __syncthreads();

    for (int it = tid; it < ROWS * On; it += NTHR) {
        int r = it / On, c = it % On;
        out[(row0 + r) * On + c] = sLogit[r][c] - sMLS[r];
    }
}

extern "C" void kernel_launch(void* const* d_in, const int* in_sizes, int n_in,
                              void* d_out, int out_size, void* d_ws, size_t ws_size,
                              hipStream_t stream) {
    const int*   x     = (const int*)d_in[0];
    const int*   xlen  = (const int*)d_in[1];
    const float* emb   = (const float*)d_in[2];
    const float* W_ih  = (const float*)d_in[3];
    const float* W_hh  = (const float*)d_in[4];
    const float* b_ih  = (const float*)d_in[5];
    const float* b_hh  = (const float*)d_in[6];
    const float* W_out = (const float*)d_in[7];
    const float* b_out = (const float*)d_in[8];
    float*       out   = (float*)d_out;

    rnn_mfma_kernel<<<NBLK, NTHR, 0, stream>>>(x, xlen, emb, W_ih, W_hh,
                                               b_ih, b_hh, W_out, b_out, out);
}

// Round 8
// 363.321 us; speedup vs baseline: 1.1157x; 1.1157x over previous
//
#include <hip/hip_runtime.h>
#include <math.h>

#define Bn 4096
#define Tn 512
#define Vn 57
#define En 20
#define Hn 128
#define On 18
#define ROWS 16          // batch rows per block (= MFMA N)
#define NTHR 512         // 8 waves (2/SIMD), one 16-col tile each -> ~95 VGPRs demand
#define NBLK (Bn / ROWS) // 256 blocks -> 1 per CU (static LDS > 80KB, volatile-kept)
#define KC 5             // K = 160 = 128 (h) + 20 (emb) + 1 (bias) + 11 pad
#define NKB 20           // k-blocks of 8 halfs
#define BUFH (NKB * 16 * 8)  // 2560 halfs per fragment-major buffer
#define ESTR 40          // embT row stride (halfs)
#define XSTR 513         // staged x row stride (ints): bank=(r+t)%32, conflict-free
#define HFSTR 132        // final-h fp32 row stride

typedef _Float16 half8  __attribute__((ext_vector_type(8)));
typedef _Float16 half4  __attribute__((ext_vector_type(4)));
typedef float    floatx4 __attribute__((ext_vector_type(4)));

__device__ __forceinline__ float fast_tanh(float x) {
    float e = __expf(2.0f * x);
    return 1.0f - __fdividef(2.0f, e + 1.0f);
}

// (512, 2): 8 waves = 2/EU min -> VGPR cap 256. Per-wave demand ~95 -> NO spill.
// R3-R7 all spilled the loop-invariant weight fragments (FETCH_SIZE 4.5GB =
// per-step scratch refills); this config is sized so spilling is impossible.
__launch_bounds__(NTHR, 2)
__global__ void rnn_mfma_kernel(const int* __restrict__ x,
                                const int* __restrict__ xlen,
                                const float* __restrict__ emb,
                                const float* __restrict__ W_ih,
                                const float* __restrict__ W_hh,
                                const float* __restrict__ b_ih,
                                const float* __restrict__ b_hh,
                                const float* __restrict__ W_out,
                                const float* __restrict__ b_out,
                                float* __restrict__ out)
{
    // Fragment-major B operand: slot s = kblock*16 + batch_row holds halfs
    // [kblock*8 .. +8) of that row. Wave b128 read = 64 consecutive slots
    // (conflict-free); h-store = 64 consecutive 8B half-slots (conflict-free).
    __shared__ __align__(16) _Float16 sB[2][BUFH];
    __shared__ __align__(16) _Float16 sEmb[Vn * ESTR];  // cols 0..19 emb, 20 = 1.0, rest 0
    __shared__ __align__(16) float    sHf[ROWS * HFSTR];
    __shared__ int sX[ROWS * XSTR];
    __shared__ float sLogit[ROWS][On];
    __shared__ float sMLS[ROWS];
    __shared__ float sPad[6200];   // 24.8KB pad: total ~82KB -> exactly 1 block/CU

    const int tid  = threadIdx.x;
    const int blk  = blockIdx.x;
    const int row0 = blk * ROWS;

    // volatile touch keeps sPad (and the 1-block/CU LDS footprint) alive
    ((volatile float*)sPad)[tid % 6200] = 0.0f;

    const int w    = tid >> 6;       // wave 0..7 -> cols [16w, 16w+16)
    const int lane = tid & 63;
    const int n    = lane & 15;      // MFMA lane index (batch for B/C, row-in-tile for A)
    const int q    = lane >> 4;      // quad
    const bool stager = (w >= 4) && (lane < 16);   // waves 4..7 stage xe kblock 16+(w-4)
    const int  wk     = (w >= 4) ? (w - 4) : 0;

    // ---- A operand (static in VGPRs): rows 16w+n of [W_hh | W_ih | bias | 0],
    //      fp16 hi + 2048*lo residual. 40 VGPRs.
    half8 Ah[KC], Al[KC];
    #pragma unroll
    for (int kc = 0; kc < 4; ++kc) {
        const float* p = &W_hh[(16 * w + n) * Hn + kc * 32 + q * 8];
        #pragma unroll
        for (int i = 0; i < 8; ++i) {
            float v = p[i];
            _Float16 hi = (_Float16)v;
            Ah[kc][i] = hi;
            Al[kc][i] = (_Float16)((v - (float)hi) * 2048.0f);
        }
    }
    {   // kc=4: W_ih cols 0..19, bias at k-col 20, zero beyond
        #pragma unroll
        for (int i = 0; i < 8; ++i) {
            int e = q * 8 + i;
            float v = 0.0f;
            if (e < En)       v = W_ih[(16 * w + n) * En + e];
            else if (e == 20) v = b_ih[16 * w + n] + b_hh[16 * w + n];
            _Float16 hi = (_Float16)v;
            Ah[4][i] = hi;
            Al[4][i] = (_Float16)((v - (float)hi) * 2048.0f);
        }
    }

    // ---- build embT (fp16) with constant-1 bias column
    for (int idx = tid; idx < Vn * 32; idx += NTHR) {
        int c = idx >> 5, j = idx & 31;
        float v = (j < En) ? emb[c * En + j] : (j == 20 ? 1.0f : 0.0f);
        sEmb[c * ESTR + j] = (_Float16)v;
    }
    // ---- stage vocab ids (int4-vectorized; 512 % 4 == 0 -> no row crossing)
    for (int idx = tid * 4; idx < ROWS * Tn; idx += NTHR * 4) {
        int4 v = *(const int4*)&x[row0 * Tn + idx];
        int r = idx >> 9, t = idx & 511;
        sX[r * XSTR + t]     = v.x;
        sX[r * XSTR + t + 1] = v.y;
        sX[r * XSTR + t + 2] = v.z;
        sX[r * XSTR + t + 3] = v.w;
    }
    // ---- zero both fragment buffers (h0 = 0)
    for (int idx = tid; idx < 2 * BUFH / 8; idx += NTHR)
        ((float4*)sB)[idx] = make_float4(0.f, 0.f, 0.f, 0.f);
    __syncthreads();

    const int Lmax  = xlen[row0];    // sorted descending -> block trip count
    const int len_n = xlen[row0 + n];

    // ---- xe(0) staging (waves 4..7, lanes 0..15)
    if (stager) {
        int id0 = sX[lane * XSTR + 0];
        half8 xe0 = *(const half8*)&sEmb[id0 * ESTR + wk * 8];
        *(half8*)&sB[0][(16 + wk) * 128 + lane * 8] = xe0;
    }
    __syncthreads();

    float hreg[4] = {0.f, 0.f, 0.f, 0.f};

    const int bbase = q * 128 + n * 8;                       // B-read lane base (halfs)
    const int kbA   = 2 * w + (q >> 1);                      // h-store kblock
    const int sadr  = kbA * 128 + n * 8 + 4 * (q & 1);       // h-store addr (halfs)

    // two-step id pipeline (staging waves only): id_use = token at t+1
    int id_use = 0;
    if (stager) id_use = sX[lane * XSTR + (Lmax > 1 ? 1 : 0)];

    for (int t = 0; t < Lmax; ++t) {
        const _Float16* bp = &sB[t & 1][0];
        _Float16*       np = &sB[(t & 1) ^ 1][0];

        // xe(t+1) gather from the register-carried id (issues right after barrier)
        half8 xe;
        int id_next = 0;
        if (stager) {
            xe = *(const half8*)&sEmb[id_use * ESTR + wk * 8];
            int tnn = (t + 2 < Lmax) ? t + 2 : Lmax - 1;
            id_next = sX[lane * XSTR + tnn];
        }

        // B operand: 5 b128 reads, 64 consecutive 16B slots each -> conflict-free
        half8 b[KC];
        #pragma unroll
        for (int kc = 0; kc < KC; ++kc)
            b[kc] = *(const half8*)&bp[bbase + kc * 512];

        // D = [W_hh|W_ih|b] . [h; xe; 1], hi + lo/2048 split
        floatx4 ah = {0.f, 0.f, 0.f, 0.f};
        floatx4 al = {0.f, 0.f, 0.f, 0.f};
        #pragma unroll
        for (int kc = 0; kc < KC; ++kc) {
            ah = __builtin_amdgcn_mfma_f32_16x16x32_f16(Ah[kc], b[kc], ah, 0, 0, 0);
            al = __builtin_amdgcn_mfma_f32_16x16x32_f16(Al[kc], b[kc], al, 0, 0, 0);
        }

        // C layout: lane(n,q) reg i -> h_col 16w+4q+i, batch n
        const bool upd = (t < len_n);
        half4 s0;
        #pragma unroll
        for (int i = 0; i < 4; ++i) {
            float v = fast_tanh(ah[i] + al[i] * (1.0f / 2048.0f));
            hreg[i] = upd ? v : hreg[i];
            s0[i] = (_Float16)hreg[i];
        }
        *(half4*)&np[sadr] = s0;   // 64 consecutive 8B half-slots -> conflict-free
        if (stager)
            *(half8*)&np[(16 + wk) * 128 + lane * 8] = xe;

        id_use = id_next;
        __syncthreads();   // double-buffered -> one barrier per step
    }

    // ---- publish final fp32 h
    {
        float4 f0;
        f0.x = hreg[0]; f0.y = hreg[1]; f0.z = hreg[2]; f0.w = hreg[3];
        *(float4*)&sHf[n * HFSTR + 16 * w + 4 * q] = f0;
    }
    __syncthreads();

    // ---- epilogue: logits = relu(h) @ W_out^T + b_out, then log_softmax
    for (int it = tid; it < ROWS * On; it += NTHR) {
        int r = it / On, c = it % On;
        float acc = b_out[c];
        for (int k = 0; k < Hn; ++k) {
            float hv = sHf[r * HFSTR + k];
            hv = hv > 0.0f ? hv : 0.0f;
            acc = fmaf(hv, W_out[c * Hn + k], acc);
        }
        sLogit[r][c] = acc;
    }
    __syncthreads();

    if (tid < ROWS) {
        float m = -INFINITY;
        #pragma unroll
        for (int c = 0; c < On; ++c) m = fmaxf(m, sLogit[tid][c]);
        float s = 0.0f;
        #pragma unroll
        for (int c = 0; c < On; ++c) s += __expf(sLogit[tid][c] - m);
        sMLS[tid] = m + __logf(s);
    }
    __syncthreads();

    for (int it = tid; it < ROWS * On; it += NTHR) {
        int r = it / On, c = it % On;
        out[(row0 + r) * On + c] = sLogit[r][c] - sMLS[r];
    }
}

extern "C" void kernel_launch(void* const* d_in, const int* in_sizes, int n_in,
                              void* d_out, int out_size, void* d_ws, size_t ws_size,
                              hipStream_t stream) {
    const int*   x     = (const int*)d_in[0];
    const int*   xlen  = (const int*)d_in[1];
    const float* emb   = (const float*)d_in[2];
    const float* W_ih  = (const float*)d_in[3];
    const float* W_hh  = (const float*)d_in[4];
    const float* b_ih  = (const float*)d_in[5];
    const float* b_hh  = (const float*)d_in[6];
    const float* W_out = (const float*)d_in[7];
    const float* b_out = (const float*)d_in[8];
    float*       out   = (float*)d_out;

    rnn_mfma_kernel<<<NBLK, NTHR, 0, stream>>>(x, xlen, emb, W_ih, W_hh,
                                               b_ih, b_hh, W_out, b_out, out);
}

// Round 9
// 321.373 us; speedup vs baseline: 1.2614x; 1.1305x over previous
//
#include <hip/hip_runtime.h>
#include <math.h>

#define Bn 4096
#define Tn 512
#define Vn 57
#define En 20
#define Hn 128
#define On 18
#define ROWS 16          // batch rows per block (= MFMA N)
#define NTHR 512         // 8 waves (2/SIMD), one 16-col tile each
#define NBLK (Bn / ROWS) // 256 blocks -> 1 per CU (static LDS > 80KB, volatile-kept)
#define KC 5             // K = 160 = 128 (h) + 20 (emb) + 1 (bias) + 11 pad
#define NKB 20           // k-blocks of 8 halfs
#define BUFH (NKB * 16 * 8)  // 2560 halfs per fragment-major buffer
#define ESTR 40          // embT row stride (halfs)
#define XSTR 513         // staged x row stride (ints): bank=(r+t)%32, conflict-free
#define HFSTR 132        // final-h fp32 row stride

typedef _Float16 half8  __attribute__((ext_vector_type(8)));
typedef _Float16 half4  __attribute__((ext_vector_type(4)));
typedef float    floatx4 __attribute__((ext_vector_type(4)));

__device__ __forceinline__ float fast_tanh(float x) {
    float e = __expf(2.0f * x);
    return 1.0f - __fdividef(2.0f, e + 1.0f);
}

// (512, 2): 8 waves = 2/EU -> VGPR cap 256; demand ~70 -> no spill, full hiding.
__launch_bounds__(NTHR, 2)
__global__ void rnn_mfma_kernel(const int* __restrict__ x,
                                const int* __restrict__ xlen,
                                const float* __restrict__ emb,
                                const float* __restrict__ W_ih,
                                const float* __restrict__ W_hh,
                                const float* __restrict__ b_ih,
                                const float* __restrict__ b_hh,
                                const float* __restrict__ W_out,
                                const float* __restrict__ b_out,
                                float* __restrict__ out)
{
    // Fragment-major B operand: slot s = kblock*16 + batch_row holds halfs
    // [kblock*8 .. +8) of that row. Wave b128 read = 64 consecutive slots
    // (conflict-free); h-store = 64 consecutive 8B half-slots (conflict-free).
    __shared__ __align__(16) _Float16 sB[2][BUFH];
    __shared__ __align__(16) _Float16 sEmb[Vn * ESTR];  // cols 0..19 emb, 20 = 1.0, rest 0
    __shared__ __align__(16) float    sHf[ROWS * HFSTR];
    __shared__ int sX[ROWS * XSTR];
    __shared__ float sLogit[ROWS][On];
    __shared__ float sMLS[ROWS];
    __shared__ float sPad[6200];   // 24.8KB pad: total ~82KB -> exactly 1 block/CU

    const int tid  = threadIdx.x;
    const int blk  = blockIdx.x;
    const int row0 = blk * ROWS;

    // volatile touch keeps sPad (and the 1-block/CU LDS footprint) alive
    ((volatile float*)sPad)[tid % 6200] = 0.0f;

    const int w    = tid >> 6;       // wave 0..7 -> cols [16w, 16w+16)
    const int lane = tid & 63;
    const int n    = lane & 15;      // MFMA lane index (batch for B/C, row-in-tile for A)
    const int q    = lane >> 4;      // quad
    const bool stager = (w >= 4) && (lane < 16);   // waves 4..7 stage xe kblock 16+(w-4)
    const int  wk     = (w >= 4) ? (w - 4) : 0;

    // ---- A operand (static in VGPRs): rows 16w+n of [W_hh | W_ih | bias | 0],
    //      fp16 (hi only; lo-residual dropped -- error class matches fp16-h storage)
    half8 Ah[KC];
    #pragma unroll
    for (int kc = 0; kc < 4; ++kc) {
        const float* p = &W_hh[(16 * w + n) * Hn + kc * 32 + q * 8];
        #pragma unroll
        for (int i = 0; i < 8; ++i)
            Ah[kc][i] = (_Float16)p[i];
    }
    {   // kc=4: W_ih cols 0..19, bias at k-col 20, zero beyond
        #pragma unroll
        for (int i = 0; i < 8; ++i) {
            int e = q * 8 + i;
            float v = 0.0f;
            if (e < En)       v = W_ih[(16 * w + n) * En + e];
            else if (e == 20) v = b_ih[16 * w + n] + b_hh[16 * w + n];
            Ah[4][i] = (_Float16)v;
        }
    }

    // ---- build embT (fp16) with constant-1 bias column
    for (int idx = tid; idx < Vn * 32; idx += NTHR) {
        int c = idx >> 5, j = idx & 31;
        float v = (j < En) ? emb[c * En + j] : (j == 20 ? 1.0f : 0.0f);
        sEmb[c * ESTR + j] = (_Float16)v;
    }
    // ---- stage vocab ids (int4-vectorized; 512 % 4 == 0 -> no row crossing)
    for (int idx = tid * 4; idx < ROWS * Tn; idx += NTHR * 4) {
        int4 v = *(const int4*)&x[row0 * Tn + idx];
        int r = idx >> 9, t = idx & 511;
        sX[r * XSTR + t]     = v.x;
        sX[r * XSTR + t + 1] = v.y;
        sX[r * XSTR + t + 2] = v.z;
        sX[r * XSTR + t + 3] = v.w;
    }
    // ---- zero both fragment buffers (h0 = 0)
    for (int idx = tid; idx < 2 * BUFH / 8; idx += NTHR)
        ((float4*)sB)[idx] = make_float4(0.f, 0.f, 0.f, 0.f);
    __syncthreads();

    const int Lmax  = xlen[row0];    // sorted descending -> block trip count
    const int len_n = xlen[row0 + n];

    // ---- xe(0) staging (waves 4..7, lanes 0..15)
    if (stager) {
        int id0 = sX[lane * XSTR + 0];
        half8 xe0 = *(const half8*)&sEmb[id0 * ESTR + wk * 8];
        *(half8*)&sB[0][(16 + wk) * 128 + lane * 8] = xe0;
    }
    __syncthreads();

    float hreg[4] = {0.f, 0.f, 0.f, 0.f};

    const int bbase = q * 128 + n * 8;                       // B-read lane base (halfs)
    const int kbA   = 2 * w + (q >> 1);                      // h-store kblock
    const int sadr  = kbA * 128 + n * 8 + 4 * (q & 1);       // h-store addr (halfs)

    // two-step id pipeline (staging waves only): id_use = token at t+1
    int id_use = 0;
    if (stager) id_use = sX[lane * XSTR + (Lmax > 1 ? 1 : 0)];

    for (int t = 0; t < Lmax; ++t) {
        const _Float16* bp = &sB[t & 1][0];
        _Float16*       np = &sB[(t & 1) ^ 1][0];

        // B operand: 5 b128 reads, 64 consecutive 16B slots each -> conflict-free
        half8 b[KC];
        #pragma unroll
        for (int kc = 0; kc < KC; ++kc)
            b[kc] = *(const half8*)&bp[bbase + kc * 512];

        // xe(t+1) gather from the register-carried id (off the MFMA chain)
        half8 xe;
        int id_next = 0;
        if (stager) {
            xe = *(const half8*)&sEmb[id_use * ESTR + wk * 8];
            int tnn = (t + 2 < Lmax) ? t + 2 : Lmax - 1;
            id_next = sX[lane * XSTR + tnn];
        }

        // D = [W_hh|W_ih|b] . [h; xe; 1] -- even/odd accumulator split:
        // two independent MFMA chains (3-deep and 2-deep) instead of one 5-deep
        floatx4 aE = {0.f, 0.f, 0.f, 0.f};
        floatx4 aO = {0.f, 0.f, 0.f, 0.f};
        aE = __builtin_amdgcn_mfma_f32_16x16x32_f16(Ah[0], b[0], aE, 0, 0, 0);
        aO = __builtin_amdgcn_mfma_f32_16x16x32_f16(Ah[1], b[1], aO, 0, 0, 0);
        aE = __builtin_amdgcn_mfma_f32_16x16x32_f16(Ah[2], b[2], aE, 0, 0, 0);
        aO = __builtin_amdgcn_mfma_f32_16x16x32_f16(Ah[3], b[3], aO, 0, 0, 0);
        aE = __builtin_amdgcn_mfma_f32_16x16x32_f16(Ah[4], b[4], aE, 0, 0, 0);

        // C layout: lane(n,q) reg i -> h_col 16w+4q+i, batch n
        const bool upd = (t < len_n);
        half4 s0;
        #pragma unroll
        for (int i = 0; i < 4; ++i) {
            float v = fast_tanh(aE[i] + aO[i]);
            hreg[i] = upd ? v : hreg[i];
            s0[i] = (_Float16)hreg[i];
        }
        *(half4*)&np[sadr] = s0;   // 64 consecutive 8B half-slots -> conflict-free
        if (stager)
            *(half8*)&np[(16 + wk) * 128 + lane * 8] = xe;

        id_use = id_next;
        __syncthreads();   // double-buffered -> one barrier per step
    }

    // ---- publish final fp32 h
    {
        float4 f0;
        f0.x = hreg[0]; f0.y = hreg[1]; f0.z = hreg[2]; f0.w = hreg[3];
        *(float4*)&sHf[n * HFSTR + 16 * w + 4 * q] = f0;
    }
    __syncthreads();

    // ---- epilogue: logits = relu(h) @ W_out^T + b_out, then log_softmax
    for (int it = tid; it < ROWS * On; it += NTHR) {
        int r = it / On, c = it % On;
        float acc = b_out[c];
        for (int k = 0; k < Hn; ++k) {
            float hv = sHf[r * HFSTR + k];
            hv = hv > 0.0f ? hv : 0.0f;
            acc = fmaf(hv, W_out[c * Hn + k], acc);
        }
        sLogit[r][c] = acc;
    }
    __syncthreads();

    if (tid < ROWS) {
        float m = -INFINITY;
        #pragma unroll
        for (int c = 0; c < On; ++c) m = fmaxf(m, sLogit[tid][c]);
        float s = 0.0f;
        #pragma unroll
        for (int c = 0; c < On; ++c) s += __expf(sLogit[tid][c] - m);
        sMLS[tid] = m + __logf(s);
    }
    __syncthreads();

    for (int it = tid; it < ROWS * On; it += NTHR) {
        int r = it / On, c = it % On;
        out[(row0 + r) * On + c] = sLogit[r][c] - sMLS[r];
    }
}

extern "C" void kernel_launch(void* const* d_in, const int* in_sizes, int n_in,
                              void* d_out, int out_size, void* d_ws, size_t ws_size,
                              hipStream_t stream) {
    const int*   x     = (const int*)d_in[0];
    const int*   xlen  = (const int*)d_in[1];
    const float* emb   = (const float*)d_in[2];
    const float* W_ih  = (const float*)d_in[3];
    const float* W_hh  = (const float*)d_in[4];
    const float* b_ih  = (const float*)d_in[5];
    const float* b_hh  = (const float*)d_in[6];
    const float* W_out = (const float*)d_in[7];
    const float* b_out = (const float*)d_in[8];
    float*       out   = (float*)d_out;

    rnn_mfma_kernel<<<NBLK, NTHR, 0, stream>>>(x, xlen, emb, W_ih, W_hh,
                                               b_ih, b_hh, W_out, b_out, out);
}